// Round 11
// baseline (109.177 us; speedup 1.0000x reference)
//
#include <hip/hip_runtime.h>

#define TOKENS 8192
#define EXPERTS 64
#define HIDDEN 4096
#define KSPLIT 8                 // K-segments (grid dim)
#define KSEG (HIDDEN / KSPLIT)   // 512 k per block
#define NCH (KSEG / 32)          // 16 chunks of K=32
#define BM 64                    // tokens per block (16 per wave)

typedef __attribute__((ext_vector_type(8))) short bf16x8;
typedef __attribute__((ext_vector_type(4))) float f32x4;

__device__ __forceinline__ unsigned short bf16_rne(float f) {
    unsigned u = __float_as_uint(f);
    return (unsigned short)((u + 0x7FFFu + ((u >> 16) & 1u)) >> 16);
}

// split 8 x f32 -> hi (RNE) + lo (trunc) bf16x8
__device__ __forceinline__ void split8(const float4& f0, const float4& f1,
                                       bf16x8& h, bf16x8& l) {
    const float fv[8] = {f0.x, f0.y, f0.z, f0.w, f1.x, f1.y, f1.z, f1.w};
#pragma unroll
    for (int j = 0; j < 8; ++j) {
        const unsigned u = __float_as_uint(fv[j]);
        const unsigned hb = (u + 0x7FFFu + ((u >> 16) & 1u)) >> 16;
        const float hf = __uint_as_float(hb << 16);
        h[j] = (short)hb;
        l[j] = (short)(__float_as_uint(fv[j] - hf) >> 16);
    }
}

// ---------------------------------------------------------------------------
// Kernel A: split w into hi/lo bf16 planes; thread 0 also zeroes flag_cnt.
// ---------------------------------------------------------------------------
__global__ void prep_w(const float* __restrict__ w,
                       unsigned short* __restrict__ wh,
                       unsigned short* __restrict__ wl,
                       int* __restrict__ flag_cnt) {
    const int i = blockIdx.x * 256 + threadIdx.x;
    if (i == 0) flag_cnt[0] = 0;
    const float f = w[i];
    const unsigned short hb = bf16_rne(f);
    const float hf = __uint_as_float(((unsigned)hb) << 16);
    wh[i] = hb;
    wl[i] = bf16_rne(f - hf);
}

// ---------------------------------------------------------------------------
// Kernel B: spill-proof streaming GEMM partial.
// Grid = 128 token-groups x 8 K-segments = 1024 blocks, 256 thr / 4 waves.
// Wave w owns tokens [t0+w*16,+16) x all 64 experts; K=512 in 16 chunks of 32.
// B chunk (8KB: hi+lo interleaved per row, 128B row stride, (r&7)<<4 swizzle)
// double-buffered in 16KB LDS. A in 2-deep named regs. One barrier per chunk;
// loads for chunk i+1 issued at top of iter i (one full compute phase cover).
// Live state ~75 VGPR; __launch_bounds__(256,5) caps at 102 -> no spill.
// ---------------------------------------------------------------------------
__global__ __launch_bounds__(256, 5)
void gemm_partial(const float* __restrict__ x,
                  const unsigned short* __restrict__ whb,
                  const unsigned short* __restrict__ wlb,
                  float* __restrict__ part) {
    __shared__ unsigned short Bs[2][EXPERTS][64];   // 16 KB, row = 64B hi | 64B lo
    const int tid = threadIdx.x;
    const int w = tid >> 6;
    const int lane = tid & 63;
    const int g = lane >> 4;              // k-octet
    const int c = lane & 15;              // token row (A) / expert col (B)
    const int t0 = (blockIdx.x >> 3) * BM;
    const int ks0 = blockIdx.x & 7;
    const int k0 = ks0 * KSEG;

    // ---- B staging geometry: 4 threads per expert row ----
    const int brow = tid >> 2;            // 0..63
    const int qi = tid & 3;
    const int swb = (brow & 7) << 4;
    const int obh = (qi * 16) ^ swb;              // hi 16B slot within 128B row
    const int obl = (64 + qi * 16) ^ swb;         // lo 16B slot
    const unsigned short* gbh = whb + (size_t)brow * HIDDEN + k0 + qi * 8;
    const unsigned short* gbl = wlb + (size_t)brow * HIDDEN + k0 + qi * 8;
    char* const wbase = (char*)&Bs[0][0][0] + brow * 128;

    // ---- B read geometry: row r=n*16+c, swizzle depends only on c ----
    const int swr = (c & 7) << 4;
    const int ohr = (g * 16) ^ swr;
    const int olr = (64 + g * 16) ^ swr;
    const char* const rdbase = (const char*)&Bs[0][0][0] + c * 128;

    // ---- A geometry ----
    const float* xa = x + (size_t)(t0 + w * 16 + c) * HIDDEN + k0 + g * 8;

    uint4 rbh, rbl;
    float4 aC0, aC1, aN0, aN1;
    f32x4 acc[4];
#pragma unroll
    for (int n = 0; n < 4; ++n) acc[n] = (f32x4)0.0f;

#define BLOAD(ch)                                                        \
    do {                                                                 \
        rbh = *(const uint4*)(gbh + (ch) * 32);                          \
        rbl = *(const uint4*)(gbl + (ch) * 32);                          \
    } while (0)
#define BWRITE(b)                                                        \
    do {                                                                 \
        *(uint4*)(wbase + (b) * 8192 + obh) = rbh;                       \
        *(uint4*)(wbase + (b) * 8192 + obl) = rbl;                       \
    } while (0)
#define COMPUTE(b, A0, A1)                                               \
    do {                                                                 \
        bf16x8 ah, al;                                                   \
        split8(A0, A1, ah, al);                                          \
        _Pragma("unroll")                                                \
        for (int n = 0; n < 4; ++n) {                                    \
            const bf16x8 bh =                                            \
                *(const bf16x8*)(rdbase + (b) * 8192 + n * 2048 + ohr);  \
            const bf16x8 bl =                                            \
                *(const bf16x8*)(rdbase + (b) * 8192 + n * 2048 + olr);  \
            acc[n] = __builtin_amdgcn_mfma_f32_16x16x32_bf16(            \
                ah, bh, acc[n], 0, 0, 0);                                \
            acc[n] = __builtin_amdgcn_mfma_f32_16x16x32_bf16(            \
                ah, bl, acc[n], 0, 0, 0);                                \
            acc[n] = __builtin_amdgcn_mfma_f32_16x16x32_bf16(            \
                al, bh, acc[n], 0, 0, 0);                                \
        }                                                                \
    } while (0)

    // prologue: chunk 0 staged, A0 in aC
    BLOAD(0);
    aC0 = *(const float4*)(xa);
    aC1 = *(const float4*)(xa + 4);
    BWRITE(0);
    __syncthreads();

#pragma unroll 1
    for (int i = 0; i < NCH; i += 2) {
        // even sub-iter: compute buf0 with aC; prefetch chunk i+1 -> buf1/aN
        if (i + 1 < NCH) {
            BLOAD(i + 1);
            aN0 = *(const float4*)(xa + (i + 1) * 32);
            aN1 = *(const float4*)(xa + (i + 1) * 32 + 4);
        }
        COMPUTE(0, aC0, aC1);
        if (i + 1 < NCH) BWRITE(1);
        __syncthreads();
        // odd sub-iter: compute buf1 with aN; prefetch chunk i+2 -> buf0/aC
        if (i + 2 < NCH) {
            BLOAD(i + 2);
            aC0 = *(const float4*)(xa + (i + 2) * 32);
            aC1 = *(const float4*)(xa + (i + 2) * 32 + 4);
        }
        COMPUTE(1, aN0, aN1);
        if (i + 2 < NCH) BWRITE(0);
        __syncthreads();
    }
#undef BLOAD
#undef BWRITE
#undef COMPUTE

    // ---- partial write: part[t][ks][e]; C layout col=lane&15, row=g*4+r ----
#pragma unroll
    for (int rr = 0; rr < 4; ++rr) {
        const int trow = t0 + w * 16 + g * 4 + rr;
        float* pb = part + ((size_t)trow * KSPLIT + ks0) * EXPERTS;
#pragma unroll
        for (int n = 0; n < 4; ++n)
            pb[n * 16 + c] = acc[n][rr];
    }
}

// ---------------------------------------------------------------------------
// Kernel C: reduce partials -> softmax -> top-9 -> outputs + near-tie flags.
// One wave per token; lane = expert. Tie-break: lower index (lax.top_k).
// ---------------------------------------------------------------------------
__global__ __launch_bounds__(256)
void reduce_topk_kernel(const float* __restrict__ part,
                        float* __restrict__ out,
                        int* __restrict__ flag_cnt,
                        int* __restrict__ flag_list) {
    const int wid = threadIdx.x >> 6;
    const int lane = threadIdx.x & 63;
    const int t = blockIdx.x * 4 + wid;

    float logit = 0.0f;
#pragma unroll
    for (int s = 0; s < KSPLIT; ++s)
        logit += part[((size_t)t * KSPLIT + s) * EXPERTS + lane];

    float m = logit;
#pragma unroll
    for (int off = 32; off >= 1; off >>= 1) m = fmaxf(m, __shfl_xor(m, off, 64));
    const float ex = __expf(logit - m);
    float sum = ex;
#pragma unroll
    for (int off = 32; off >= 1; off >>= 1) sum += __shfl_xor(sum, off, 64);
    const float score = ex / sum;

    float v = score;
    bool sel = false;
    float v8 = 0.f, v9 = 0.f;
#pragma unroll
    for (int it = 0; it < 9; ++it) {
        float bv = v;
        int bi = lane;
#pragma unroll
        for (int off = 32; off >= 1; off >>= 1) {
            const float ov = __shfl_xor(bv, off, 64);
            const int oi = __shfl_xor(bi, off, 64);
            if (ov > bv || (ov == bv && oi < bi)) { bv = ov; bi = oi; }
        }
        if (it < 8) {
            if (lane == bi) { sel = true; v = -1.0f; }
            if (it == 7) v8 = bv;
        } else {
            v9 = bv;
        }
    }
    if (lane == 0 && (v8 - v9) < v8 * 1e-3f) {
        const int idx = atomicAdd(flag_cnt, 1);
        flag_list[idx] = t;
    }
    out[(size_t)t * EXPERTS + lane] = sel ? score : 0.f;
    out[(size_t)TOKENS * EXPERTS + (size_t)t * EXPERTS + lane] = sel ? 1.f : 0.f;
}

// ---------------------------------------------------------------------------
// Rescue: exact f32 recompute of flagged tokens (near-tie at rank 8/9).
// ---------------------------------------------------------------------------
__global__ __launch_bounds__(256)
void router_rescue(const float* __restrict__ x, const float* __restrict__ wgt,
                   float* __restrict__ out, const int* __restrict__ cnt,
                   const int* __restrict__ list) {
    __shared__ float xrow[HIDDEN];
    __shared__ float lg[EXPERTS];
    const int tid = threadIdx.x;
    const int w = tid >> 6, lane = tid & 63;
    const int n = cnt[0];
    for (int i = blockIdx.x; i < n; i += 256) {
        const int t = list[i];
        __syncthreads();
        for (int j = tid; j < HIDDEN / 4; j += 256)
            ((float4*)xrow)[j] = ((const float4*)(x + (size_t)t * HIDDEN))[j];
        __syncthreads();
#pragma unroll 2
        for (int ei = 0; ei < 16; ++ei) {
            const int e = w * 16 + ei;
            const float* wr = wgt + (size_t)e * HIDDEN;
            float a = 0.f;
            for (int kk = 0; kk < HIDDEN; kk += 256) {
                const float4 xv = *(const float4*)(xrow + kk + lane * 4);
                const float4 wv = *(const float4*)(wr + kk + lane * 4);
                a = fmaf(xv.x, wv.x, a); a = fmaf(xv.y, wv.y, a);
                a = fmaf(xv.z, wv.z, a); a = fmaf(xv.w, wv.w, a);
            }
#pragma unroll
            for (int off = 32; off >= 1; off >>= 1) a += __shfl_xor(a, off, 64);
            if (lane == 0) lg[e] = a;
        }
        __syncthreads();
        if (w == 0) {
            const float logit = lg[lane];
            float m = logit;
#pragma unroll
            for (int off = 32; off >= 1; off >>= 1) m = fmaxf(m, __shfl_xor(m, off, 64));
            const float ex = __expf(logit - m);
            float sum = ex;
#pragma unroll
            for (int off = 32; off >= 1; off >>= 1) sum += __shfl_xor(sum, off, 64);
            const float score = ex / sum;
            float v = score;
            bool sel = false;
#pragma unroll
            for (int it = 0; it < 8; ++it) {
                float bv = v; int bi = lane;
#pragma unroll
                for (int off = 32; off >= 1; off >>= 1) {
                    const float ov = __shfl_xor(bv, off, 64);
                    const int oi = __shfl_xor(bi, off, 64);
                    if (ov > bv || (ov == bv && oi < bi)) { bv = ov; bi = oi; }
                }
                if (lane == bi) { sel = true; v = -1.f; }
            }
            out[(size_t)t * EXPERTS + lane] = sel ? score : 0.f;
            out[(size_t)TOKENS * EXPERTS + (size_t)t * EXPERTS + lane] = sel ? 1.f : 0.f;
        }
        __syncthreads();
    }
}

// ---------------------------------------------------------------------------
extern "C" void kernel_launch(void* const* d_in, const int* in_sizes, int n_in,
                              void* d_out, int out_size, void* d_ws, size_t ws_size,
                              hipStream_t stream) {
    (void)in_sizes; (void)n_in; (void)out_size; (void)ws_size;
    const float* x = (const float*)d_in[0];       // [8192][4096] f32
    const float* w = (const float*)d_in[1];       // [64][4096] f32
    float* out = (float*)d_out;

    // ws: whb [0,512K) | wlb [512K,1M) | part [1M,17M) | flags [17M,..)
    unsigned short* whb = (unsigned short*)d_ws;
    unsigned short* wlb = (unsigned short*)((char*)d_ws + (512 << 10));
    float* part = (float*)((char*)d_ws + (1 << 20));
    int* flag_cnt = (int*)((char*)d_ws + (17 << 20));
    int* flag_list = (int*)((char*)d_ws + (17 << 20) + 256);

    prep_w<<<(EXPERTS * HIDDEN) / 256, 256, 0, stream>>>(w, whb, wlb, flag_cnt);
    gemm_partial<<<(TOKENS / BM) * KSPLIT, 256, 0, stream>>>(x, whb, wlb, part);
    reduce_topk_kernel<<<TOKENS / 4, 256, 0, stream>>>(part, out, flag_cnt, flag_list);
    router_rescue<<<256, 256, 0, stream>>>(x, w, out, flag_cnt, flag_list);
}